// Round 10
// baseline (1101.175 us; speedup 1.0000x reference)
//
#include <hip/hip_runtime.h>

// ---------------------------------------------------------------------------
// UpsampleLayer: out = Upsample2x_FIR( W @ x ) + bias.  GEMM at 64x64 (commute)
// then FIR upsample to 127x127.
// Upsample math (validated R0-R8):
//   col j (even, j=2a): g = 1*z[a-1] + 3*z[a];  (odd, j=2a+1): g = 3*z[a]+z[a+1]
//   j==0: left tap 0.  Row 2m-1 = 3*g[m-1]+g[m]; row 2m = g[m-1]+3*g[m]; /16 +b.
//
// R9 = DIAGNOSTIC ROUND. 6 upsample variants have landed 178-436us vs a ~90us
// floor and I have had no per-kernel counters since R1 (fillBuffer ~305-322us
// monopolizes top-5). This round makes both upsample structures visible by
// internal repetition (b x4 first, a x2 last so the PROVEN R4 code writes the
// final values). Reads: hbm_gbps + VALUBusy of each -> decide BW-wall vs
// issue-bound and pick the single-pass winner next round.
// ---------------------------------------------------------------------------

#define B_   16
#define CIN  512
#define COUT 512
#define S_   4096   // 64*64
#define HO   127
#define WO   127

#define REPS_A 2
#define REPS_B 4

typedef unsigned int  u32;
typedef unsigned short u16;
typedef __attribute__((ext_vector_type(8))) short  bf16x8;
typedef __attribute__((ext_vector_type(8))) u16    u16x8;
typedef __attribute__((ext_vector_type(4))) float  f32x4;
typedef __attribute__((ext_vector_type(2))) float  f32x2;

static __device__ __forceinline__ u16 f2bf(float f) {
  u32 u = __float_as_uint(f);
  u += 0x7FFFu + ((u >> 16) & 1u);   // RNE (inputs finite)
  return (u16)(u >> 16);
}
static __device__ __forceinline__ float bf2f(u16 h) {
  return __uint_as_float(((u32)h) << 16);
}
static __device__ __forceinline__ void store2(float* p, float a, float b) {
  f32x2 v; v.x = a; v.y = b;
  __builtin_memcpy(p, &v, 8);
}

#if defined(__has_builtin)
#if __has_builtin(__builtin_amdgcn_global_load_lds)
#define HAS_GLOAD 1
#endif
#endif
#ifndef HAS_GLOAD
#define HAS_GLOAD 0
#endif

#if HAS_GLOAD
static __device__ __forceinline__ void gload16(const char* g, char* l) {
  __builtin_amdgcn_global_load_lds(
      (const __attribute__((address_space(1))) unsigned int*)g,
      (__attribute__((address_space(3))) unsigned int*)l, 16, 0, 0);
}
#endif

// ---------------------------------------------------------------------------
// Tiled operand layout (wt, xt), per 128(row) x 32(k) tile = 8 KiB:
// unit u = kg*128 + r holds 8 bf16, k = tk*32 + kg*8 + e.
// ---------------------------------------------------------------------------

__global__ __launch_bounds__(256) void conv_w_kernel(
    const float* __restrict__ w, u16* __restrict__ wt) {
  int g = blockIdx.x * 256 + threadIdx.x;
  int t_idx = g >> 9;
  int u = g & 511;
  int to = t_idx >> 4, tk = t_idx & 15;
  int r = u & 127, kg = u >> 7;
  int o = to * 128 + r;
  int c = tk * 32 + kg * 8;
  const float4* src = reinterpret_cast<const float4*>(w + (size_t)o * CIN + c);
  float4 lo = src[0], hi = src[1];
  u16x8 pk;
  pk[0] = f2bf(lo.x); pk[1] = f2bf(lo.y); pk[2] = f2bf(lo.z); pk[3] = f2bf(lo.w);
  pk[4] = f2bf(hi.x); pk[5] = f2bf(hi.y); pk[6] = f2bf(hi.z); pk[7] = f2bf(hi.w);
  *reinterpret_cast<u16x8*>(wt + (size_t)g * 8) = pk;
}

__global__ __launch_bounds__(256) void conv_x_kernel(
    const float* __restrict__ x, u16* __restrict__ xt) {
  int ts = blockIdx.x, tk = blockIdx.y, b = blockIdx.z;
  int t = threadIdx.x;
  __shared__ float lf[32 * 128];
  const float* src = x + ((size_t)(b * CIN + tk * 32)) * S_ + ts * 128;
#pragma unroll
  for (int i = 0; i < 4; ++i) {
    int q = i * 256 + t;
    int c = q >> 5, sq = q & 31;
    *reinterpret_cast<float4*>(&lf[c * 128 + sq * 4]) =
        *reinterpret_cast<const float4*>(src + (size_t)c * S_ + sq * 4);
  }
  __syncthreads();
  size_t tile_base = (((size_t)(b * 32 + ts)) * 16 + tk) * 512;
#pragma unroll
  for (int i = 0; i < 2; ++i) {
    int u = i * 256 + t;
    int kg = u >> 7, r = u & 127;
    u16x8 pk;
#pragma unroll
    for (int e = 0; e < 8; ++e) pk[e] = f2bf(lf[(kg * 8 + e) * 128 + r]);
    *reinterpret_cast<u16x8*>(xt + (tile_base + u) * 8) = pk;
  }
}

// GEMM (R4 exact): 128x128 tile, BK=32, 4 waves, mfma_f32_16x16x32_bf16.
__global__ __launch_bounds__(256) void gemm_kernel(
    const u16* __restrict__ wt, const u16* __restrict__ xt,
    u16* __restrict__ z) {
  int nt = blockIdx.x, mt = blockIdx.y, b = blockIdx.z;
  int t = threadIdx.x;
  __shared__ short lds[8192];
  char* lA = (char*)&lds[0];
  char* lB = lA + 8192;

  int lane = t & 63, wid = t >> 6;
  int wr = wid >> 1, wc = wid & 1;
  int lr = lane & 15, kg = lane >> 4;

  f32x4 acc[4][4];
#pragma unroll
  for (int m = 0; m < 4; ++m)
#pragma unroll
    for (int n = 0; n < 4; ++n) acc[m][n] = f32x4{0.f, 0.f, 0.f, 0.f};

  const char* gA = (const char*)wt + (size_t)(mt * 16) * 8192;
  const char* gB = (const char*)xt + ((size_t)(b * 32 + nt)) * 16 * 8192;

  int abyte[4], bbyte[4];
#pragma unroll
  for (int m = 0; m < 4; ++m) abyte[m] = (kg * 128 + wr * 64 + m * 16 + lr) * 16;
#pragma unroll
  for (int n = 0; n < 4; ++n) bbyte[n] = (kg * 128 + wc * 64 + n * 16 + lr) * 16;

  for (int ks = 0; ks < 16; ++ks) {
    const char* pA = gA + (size_t)ks * 8192;
    const char* pB = gB + (size_t)ks * 8192;
#if HAS_GLOAD
    __syncthreads();
    gload16(pA + t * 16, lA + t * 16);
    gload16(pA + 4096 + t * 16, lA + 4096 + t * 16);
    gload16(pB + t * 16, lB + t * 16);
    gload16(pB + 4096 + t * 16, lB + 4096 + t * 16);
    __syncthreads();
#else
    u16x8 va0 = *reinterpret_cast<const u16x8*>(pA + t * 16);
    u16x8 va1 = *reinterpret_cast<const u16x8*>(pA + 4096 + t * 16);
    u16x8 vb0 = *reinterpret_cast<const u16x8*>(pB + t * 16);
    u16x8 vb1 = *reinterpret_cast<const u16x8*>(pB + 4096 + t * 16);
    __syncthreads();
    *reinterpret_cast<u16x8*>(lA + t * 16) = va0;
    *reinterpret_cast<u16x8*>(lA + 4096 + t * 16) = va1;
    *reinterpret_cast<u16x8*>(lB + t * 16) = vb0;
    *reinterpret_cast<u16x8*>(lB + 4096 + t * 16) = vb1;
    __syncthreads();
#endif
    bf16x8 av[4], bv[4];
#pragma unroll
    for (int m = 0; m < 4; ++m)
      av[m] = *reinterpret_cast<const bf16x8*>(lA + abyte[m]);
#pragma unroll
    for (int n = 0; n < 4; ++n)
      bv[n] = *reinterpret_cast<const bf16x8*>(lB + bbyte[n]);
#pragma unroll
    for (int m = 0; m < 4; ++m)
#pragma unroll
      for (int n = 0; n < 4; ++n)
        acc[m][n] = __builtin_amdgcn_mfma_f32_16x16x32_bf16(
            av[m], bv[n], acc[m][n], 0, 0, 0);
  }

  int o_b = mt * 128 + wr * 64 + kg * 4;
  int s_b = nt * 128 + wc * 64 + lr;
#pragma unroll
  for (int m = 0; m < 4; ++m)
#pragma unroll
    for (int n = 0; n < 4; ++n) {
      f32x4 v = acc[m][n];
      size_t base = ((size_t)(b * COUT + o_b + m * 16)) * S_ + (s_b + n * 16);
#pragma unroll
      for (int r = 0; r < 4; ++r) z[base + (size_t)r * S_] = f2bf(v[r]);
    }
}

// ---- DIAGNOSTIC B (runs FIRST; values overwritten by A): 1 wave per image,
// lane = (rowhalf<<5)|colgroup l; lane owns out cols [4l,4l+4) of 32 rows.
// Per z-row: 3 aligned dword loads (P/C/N, clamped; garbage masked), 4 fma ->
// g0..g3, 2 dwordx4 stores (rows 2m-1, 2m; lane31 splits: col 127 dropped).
__global__ __launch_bounds__(256) void upsample_b(
    const u16* __restrict__ z, const float* __restrict__ bias,
    float* __restrict__ out) {
  int t = threadIdx.x;
  int bo = blockIdx.x * 4 + (t >> 6);
  int lane = t & 63;
  int l = lane & 31, rh = lane >> 5;
  const u32* zi = reinterpret_cast<const u32*>(z + ((size_t)bo << 12));
  float bv = bias[bo & 511];
  float* ob = out + (size_t)bo * (HO * WO);
  int lp = (l == 0) ? 0 : (l - 1);
  int ln = (l == 31) ? 31 : (l + 1);
  float tA0 = (l == 0) ? 0.f : 1.f;
  int m0 = rh << 5;
  bool full = (l < 31);

  for (int rep = 0; rep < REPS_B; ++rep) {
    float gp0 = 0.f, gp1 = 0.f, gp2 = 0.f, gp3 = 0.f;
    if (rh) {  // halo: g of z-row 31
      const u32* r = zi + 31 * 32;
      u32 P = r[lp], C = r[l], N = r[ln];
      float zP = bf2f((u16)(P >> 16));
      float z0 = bf2f((u16)C), z1 = bf2f((u16)(C >> 16));
      float z2 = bf2f((u16)N);
      gp0 = fmaf(3.f, z0, tA0 * zP);
      gp1 = fmaf(3.f, z0, z1);
      gp2 = fmaf(3.f, z1, z0);
      gp3 = fmaf(3.f, z1, z2);
    }
    const u32* r = zi + m0 * 32;
    u32 P = r[lp], C = r[l], N = r[ln];
    for (int i = 0; i < 32; ++i) {
      int m = m0 + i;
      float zP = bf2f((u16)(P >> 16));
      float z0 = bf2f((u16)C), z1 = bf2f((u16)(C >> 16));
      float z2 = bf2f((u16)N);
      if (m < 63) { r += 32; P = r[lp]; C = r[l]; N = r[ln]; }
      float g0 = fmaf(3.f, z0, tA0 * zP);   // col 4l
      float g1 = fmaf(3.f, z0, z1);         // col 4l+1
      float g2 = fmaf(3.f, z1, z0);         // col 4l+2
      float g3 = fmaf(3.f, z1, z2);         // col 4l+3 (garbage at l=31, dropped)
      float* pe = ob + (size_t)(2 * m) * WO + 4 * l;
      if (m > 0) {  // row 2m-1 = 3*gp + g
        float* po = pe - WO;
        float v0 = fmaf(fmaf(3.f, gp0, g0), 0.0625f, bv);
        float v1 = fmaf(fmaf(3.f, gp1, g1), 0.0625f, bv);
        float v2 = fmaf(fmaf(3.f, gp2, g2), 0.0625f, bv);
        float v3 = fmaf(fmaf(3.f, gp3, g3), 0.0625f, bv);
        if (full) { float vv[4] = {v0, v1, v2, v3}; __builtin_memcpy(po, vv, 16); }
        else { po[0] = v0; po[1] = v1; po[2] = v2; }
      }
      {  // row 2m = gp + 3*g
        float v0 = fmaf(fmaf(3.f, g0, gp0), 0.0625f, bv);
        float v1 = fmaf(fmaf(3.f, g1, gp1), 0.0625f, bv);
        float v2 = fmaf(fmaf(3.f, g2, gp2), 0.0625f, bv);
        float v3 = fmaf(fmaf(3.f, g3, gp3), 0.0625f, bv);
        if (full) { float vv[4] = {v0, v1, v2, v3}; __builtin_memcpy(pe, vv, 16); }
        else { pe[0] = v0; pe[1] = v1; pe[2] = v2; }
      }
      gp0 = g0; gp1 = g1; gp2 = g2; gp3 = g3;
    }
    asm volatile("" ::: "memory");  // block DSE across reps
  }
}

// ---- A = R4 upsample exact (runs LAST -> final values; proven correct),
// wrapped in REPS_A for top-5 visibility.
__global__ __launch_bounds__(256) void upsample_a(
    const u16* __restrict__ z, const float* __restrict__ bias,
    float* __restrict__ out) {
  int t = threadIdx.x;
  int lane = t & 63;
  int gw = blockIdx.x * 4 + (t >> 6);
  int bo = gw >> 1;
  int half = gw & 1;
  int m0 = half << 5;

  const u16* zimg = z + ((size_t)bo << 12);
  float bv = bias[bo & 511];
  float* ob = out + (size_t)bo * (HO * WO) + 2 * lane;

  float wl = (lane == 0) ? 0.f : 1.f;
  bool has_j1 = (lane < 63);
  const u16* zp0 = zimg + (m0 << 6) + lane;

  for (int rep = 0; rep < REPS_A; ++rep) {
    const u16* zp = zp0;
    float hA_p = 0.f, hB_p = 0.f;
    if (half) {
      const u16* q = zp - 64;
      float zc = bf2f(q[0]);
      hA_p = fmaf(3.f, zc, bf2f(q[-1]) * wl);
      hB_p = fmaf(3.f, zc, bf2f(q[1]));
    }
    u16 c_ = zp[0], l_ = zp[-1], r_ = zp[1];

#pragma unroll 2
    for (int i = 0; i < 32; ++i) {
      int m = m0 + i;
      float zc = bf2f(c_), zl = bf2f(l_) * wl, zr = bf2f(r_);
      if (m < 63) {
        const u16* q = zp + 64;
        c_ = q[0]; l_ = q[-1]; r_ = q[1];
        zp = q;
      }
      float hA = fmaf(3.f, zc, zl);
      float hB = fmaf(3.f, zc, zr);

      float* p_even = ob + (u32)(2 * m) * WO;
      if (m > 0) {
        float* p_odd = p_even - WO;
        float v0 = fmaf(fmaf(3.f, hA_p, hA), 0.0625f, bv);
        float v1 = fmaf(fmaf(3.f, hB_p, hB), 0.0625f, bv);
        if (has_j1) store2(p_odd, v0, v1); else p_odd[0] = v0;
      }
      {
        float v0 = fmaf(fmaf(3.f, hA, hA_p), 0.0625f, bv);
        float v1 = fmaf(fmaf(3.f, hB, hB_p), 0.0625f, bv);
        if (has_j1) store2(p_even, v0, v1); else p_even[0] = v0;
      }
      hA_p = hA; hB_p = hB;
    }
    asm volatile("" ::: "memory");  // block DSE across reps
  }
}

// Fallback (no workspace).
__global__ __launch_bounds__(256) void fallback_kernel(
    const float* __restrict__ x, const float* __restrict__ w,
    const float* __restrict__ bias, float* __restrict__ out) {
  u32 idx = blockIdx.x * 256u + threadIdx.x;
  const u32 total = (u32)B_ * COUT * HO * WO;
  if (idx >= total) return;
  u32 j = idx % WO;
  u32 r1 = idx / WO;
  u32 i = r1 % HO;
  u32 bo = r1 / HO;
  int o = (int)(bo & 511u);
  int b = (int)(bo >> 9);
  int m = (int)(i >> 1), n = (int)(j >> 1);
  int ie = !(i & 1), je = !(j & 1);
  int rA = ie ? m - 1 : m;
  int cA = je ? n - 1 : n;
  float w_r0 = ie ? 1.f : 3.f, w_r1 = ie ? 3.f : 1.f;
  float w_c0 = je ? 1.f : 3.f, w_c1 = je ? 3.f : 1.f;
  const float* xb = x + (size_t)b * CIN * S_;
  float acc = 0.f;
  for (int cc = 0; cc < CIN; ++cc) {
    const float* xc = xb + (size_t)cc * S_;
    float y = 0.f;
    if (rA >= 0) {
      if (cA >= 0) y += w_r0 * w_c0 * xc[rA * 64 + cA];
      y += w_r0 * w_c1 * xc[rA * 64 + cA + 1];
    }
    if (cA >= 0) y += w_r1 * w_c0 * xc[(rA + 1) * 64 + cA];
    y += w_r1 * w_c1 * xc[(rA + 1) * 64 + cA + 1];
    acc += y * w[(size_t)o * CIN + cc];
  }
  out[idx] = acc * 0.0625f + bias[o];
}

extern "C" void kernel_launch(void* const* d_in, const int* in_sizes, int n_in,
                              void* d_out, int out_size, void* d_ws,
                              size_t ws_size, hipStream_t stream) {
  const float* x = (const float*)d_in[0];
  const float* w = (const float*)d_in[2];
  const float* bias = (const float*)d_in[3];
  float* out = (float*)d_out;

  const size_t xt_bytes = (size_t)B_ * S_ * CIN * 2;       // 64 MiB
  const size_t wt_off = xt_bytes;
  const size_t wt_bytes = (size_t)COUT * CIN * 2;          // 512 KiB
  const size_t z_off = wt_off + ((wt_bytes + 255) & ~(size_t)255);
  const size_t need = z_off + (size_t)B_ * COUT * S_ * 2;  // ~128.5 MiB
  const size_t total_out = (size_t)B_ * COUT * HO * WO;
  const u32 nblk_out = (u32)((total_out + 255) / 256);

  if (ws_size >= need) {
    u16* xt = (u16*)d_ws;
    u16* wt = (u16*)((char*)d_ws + wt_off);
    u16* zz = (u16*)((char*)d_ws + z_off);
    conv_w_kernel<<<128, 256, 0, stream>>>(w, wt);
    conv_x_kernel<<<dim3(32, 16, B_), 256, 0, stream>>>(x, xt);
    gemm_kernel<<<dim3(32, 4, B_), 256, 0, stream>>>(wt, xt, zz);
    // Diagnostic candidate first (x4 reps, visible in top-5)...
    upsample_b<<<(B_ * COUT) / 4, 256, 0, stream>>>(zz, bias, out);
    // ...then the proven R4 kernel last (x2 reps) -> final output values.
    upsample_a<<<(B_ * COUT * 2) / 4, 256, 0, stream>>>(zz, bias, out);
  } else {
    fallback_kernel<<<nblk_out, 256, 0, stream>>>(x, w, bias, out);
  }
}

// Round 11
// 279.957 us; speedup vs baseline: 3.9334x; 3.9334x over previous
//
#include <hip/hip_runtime.h>

// ---------------------------------------------------------------------------
// UpsampleLayer: out = Upsample2x_FIR( W @ x ) + bias.  GEMM at 64x64 (commute)
// then FIR upsample to 127x127.
// Upsample math (validated R0-R9):
//   col j (even, j=2a): g = 1*z[a-1] + 3*z[a];  (odd, j=2a+1): g = 3*z[a]+z[a+1]
//   j==0: left tap 0.  Row 2m-1 = 3*g[m-1]+g[m]; row 2m = g[m-1]+3*g[m]; /16 +b.
//
// R9 diagnostic verdict: upsample is LATENCY-bound (VALUBusy 12%, hbm 42%,
// occ 60%) -- serial 32-iter g-carry chain per wave, both pipes idle.
// R10: 8 waves/image, each half-wave owns 4 z-rows (+1 halo) -> chain len 4,
// 65536 waves, 2 independent chains/wave. Same dword-load/dwordx4-store body
// as R9's upsample_b (math symbolically matched to validated formulas).
// ---------------------------------------------------------------------------

#define B_   16
#define CIN  512
#define COUT 512
#define S_   4096   // 64*64
#define HO   127
#define WO   127

typedef unsigned int  u32;
typedef unsigned short u16;
typedef __attribute__((ext_vector_type(8))) short  bf16x8;
typedef __attribute__((ext_vector_type(8))) u16    u16x8;
typedef __attribute__((ext_vector_type(4))) float  f32x4;

static __device__ __forceinline__ u16 f2bf(float f) {
  u32 u = __float_as_uint(f);
  u += 0x7FFFu + ((u >> 16) & 1u);   // RNE (inputs finite)
  return (u16)(u >> 16);
}
static __device__ __forceinline__ float bf2f(u16 h) {
  return __uint_as_float(((u32)h) << 16);
}

#if defined(__has_builtin)
#if __has_builtin(__builtin_amdgcn_global_load_lds)
#define HAS_GLOAD 1
#endif
#endif
#ifndef HAS_GLOAD
#define HAS_GLOAD 0
#endif

#if HAS_GLOAD
static __device__ __forceinline__ void gload16(const char* g, char* l) {
  __builtin_amdgcn_global_load_lds(
      (const __attribute__((address_space(1))) unsigned int*)g,
      (__attribute__((address_space(3))) unsigned int*)l, 16, 0, 0);
}
#endif

// ---------------------------------------------------------------------------
// Tiled operand layout (wt, xt), per 128(row) x 32(k) tile = 8 KiB:
// unit u = kg*128 + r holds 8 bf16, k = tk*32 + kg*8 + e.
// ---------------------------------------------------------------------------

__global__ __launch_bounds__(256) void conv_w_kernel(
    const float* __restrict__ w, u16* __restrict__ wt) {
  int g = blockIdx.x * 256 + threadIdx.x;
  int t_idx = g >> 9;
  int u = g & 511;
  int to = t_idx >> 4, tk = t_idx & 15;
  int r = u & 127, kg = u >> 7;
  int o = to * 128 + r;
  int c = tk * 32 + kg * 8;
  const float4* src = reinterpret_cast<const float4*>(w + (size_t)o * CIN + c);
  float4 lo = src[0], hi = src[1];
  u16x8 pk;
  pk[0] = f2bf(lo.x); pk[1] = f2bf(lo.y); pk[2] = f2bf(lo.z); pk[3] = f2bf(lo.w);
  pk[4] = f2bf(hi.x); pk[5] = f2bf(hi.y); pk[6] = f2bf(hi.z); pk[7] = f2bf(hi.w);
  *reinterpret_cast<u16x8*>(wt + (size_t)g * 8) = pk;
}

__global__ __launch_bounds__(256) void conv_x_kernel(
    const float* __restrict__ x, u16* __restrict__ xt) {
  int ts = blockIdx.x, tk = blockIdx.y, b = blockIdx.z;
  int t = threadIdx.x;
  __shared__ float lf[32 * 128];
  const float* src = x + ((size_t)(b * CIN + tk * 32)) * S_ + ts * 128;
#pragma unroll
  for (int i = 0; i < 4; ++i) {
    int q = i * 256 + t;
    int c = q >> 5, sq = q & 31;
    *reinterpret_cast<float4*>(&lf[c * 128 + sq * 4]) =
        *reinterpret_cast<const float4*>(src + (size_t)c * S_ + sq * 4);
  }
  __syncthreads();
  size_t tile_base = (((size_t)(b * 32 + ts)) * 16 + tk) * 512;
#pragma unroll
  for (int i = 0; i < 2; ++i) {
    int u = i * 256 + t;
    int kg = u >> 7, r = u & 127;
    u16x8 pk;
#pragma unroll
    for (int e = 0; e < 8; ++e) pk[e] = f2bf(lf[(kg * 8 + e) * 128 + r]);
    *reinterpret_cast<u16x8*>(xt + (tile_base + u) * 8) = pk;
  }
}

// GEMM (R4 exact): 128x128 tile, BK=32, 4 waves, mfma_f32_16x16x32_bf16.
__global__ __launch_bounds__(256) void gemm_kernel(
    const u16* __restrict__ wt, const u16* __restrict__ xt,
    u16* __restrict__ z) {
  int nt = blockIdx.x, mt = blockIdx.y, b = blockIdx.z;
  int t = threadIdx.x;
  __shared__ short lds[8192];
  char* lA = (char*)&lds[0];
  char* lB = lA + 8192;

  int lane = t & 63, wid = t >> 6;
  int wr = wid >> 1, wc = wid & 1;
  int lr = lane & 15, kg = lane >> 4;

  f32x4 acc[4][4];
#pragma unroll
  for (int m = 0; m < 4; ++m)
#pragma unroll
    for (int n = 0; n < 4; ++n) acc[m][n] = f32x4{0.f, 0.f, 0.f, 0.f};

  const char* gA = (const char*)wt + (size_t)(mt * 16) * 8192;
  const char* gB = (const char*)xt + ((size_t)(b * 32 + nt)) * 16 * 8192;

  int abyte[4], bbyte[4];
#pragma unroll
  for (int m = 0; m < 4; ++m) abyte[m] = (kg * 128 + wr * 64 + m * 16 + lr) * 16;
#pragma unroll
  for (int n = 0; n < 4; ++n) bbyte[n] = (kg * 128 + wc * 64 + n * 16 + lr) * 16;

  for (int ks = 0; ks < 16; ++ks) {
    const char* pA = gA + (size_t)ks * 8192;
    const char* pB = gB + (size_t)ks * 8192;
#if HAS_GLOAD
    __syncthreads();
    gload16(pA + t * 16, lA + t * 16);
    gload16(pA + 4096 + t * 16, lA + 4096 + t * 16);
    gload16(pB + t * 16, lB + t * 16);
    gload16(pB + 4096 + t * 16, lB + 4096 + t * 16);
    __syncthreads();
#else
    u16x8 va0 = *reinterpret_cast<const u16x8*>(pA + t * 16);
    u16x8 va1 = *reinterpret_cast<const u16x8*>(pA + 4096 + t * 16);
    u16x8 vb0 = *reinterpret_cast<const u16x8*>(pB + t * 16);
    u16x8 vb1 = *reinterpret_cast<const u16x8*>(pB + 4096 + t * 16);
    __syncthreads();
    *reinterpret_cast<u16x8*>(lA + t * 16) = va0;
    *reinterpret_cast<u16x8*>(lA + 4096 + t * 16) = va1;
    *reinterpret_cast<u16x8*>(lB + t * 16) = vb0;
    *reinterpret_cast<u16x8*>(lB + 4096 + t * 16) = vb1;
    __syncthreads();
#endif
    bf16x8 av[4], bv[4];
#pragma unroll
    for (int m = 0; m < 4; ++m)
      av[m] = *reinterpret_cast<const bf16x8*>(lA + abyte[m]);
#pragma unroll
    for (int n = 0; n < 4; ++n)
      bv[n] = *reinterpret_cast<const bf16x8*>(lB + bbyte[n]);
#pragma unroll
    for (int m = 0; m < 4; ++m)
#pragma unroll
      for (int n = 0; n < 4; ++n)
        acc[m][n] = __builtin_amdgcn_mfma_f32_16x16x32_bf16(
            av[m], bv[n], acc[m][n], 0, 0, 0);
  }

  int o_b = mt * 128 + wr * 64 + kg * 4;
  int s_b = nt * 128 + wc * 64 + lr;
#pragma unroll
  for (int m = 0; m < 4; ++m)
#pragma unroll
    for (int n = 0; n < 4; ++n) {
      f32x4 v = acc[m][n];
      size_t base = ((size_t)(b * COUT + o_b + m * 16)) * S_ + (s_b + n * 16);
#pragma unroll
      for (int r = 0; r < 4; ++r) z[base + (size_t)r * S_] = f2bf(v[r]);
    }
}

// R10 upsample: 8 waves per (b,o) image; wave = (bo, rowgroup rg). Each
// 32-lane half-wave owns 4 z-rows (m0 = rg*8 + rh*4) + 1 halo row -> serial
// g-carry chain length 4 (was 32). Lane l owns out cols [4l, 4l+4):
//   per row ONE dword C = z cols {2l, 2l+1} + neighbor dwords P (l-1), N (l+1)
//   g0 = 3*z0 + zP (tap0 at l==0), g1 = 3*z0+z1, g2 = z0+3*z1, g3 = 3*z1+z2
//   row 2m-1 = 3*g_prev + g; row 2m = g_prev + 3*g; *1/16 + bias.
// 65536 waves total -> full occupancy, deep MLP.
__global__ __launch_bounds__(256) void upsample_kernel(
    const u16* __restrict__ z, const float* __restrict__ bias,
    float* __restrict__ out) {
  int t = threadIdx.x;
  int gw = blockIdx.x * 4 + (t >> 6);  // global wave id
  int bo = gw >> 3;                    // b*512 + o
  int rg = gw & 7;                     // row group
  int lane = t & 63;
  int l = lane & 31, rh = lane >> 5;
  int m0 = rg * 8 + rh * 4;            // this half-wave: z rows m0..m0+3

  const u32* zi = reinterpret_cast<const u32*>(z + ((size_t)bo << 12));
  float bv = bias[bo & 511];
  float* ob = out + (size_t)bo * (HO * WO);

  int lp = (l == 0) ? 0 : (l - 1);
  int ln = (l == 31) ? 31 : (l + 1);
  float tA0 = (l == 0) ? 0.f : 1.f;
  bool full = (l < 31);

  float gp0 = 0.f, gp1 = 0.f, gp2 = 0.f, gp3 = 0.f;
  if (m0 > 0) {  // halo: g of z-row m0-1
    const u32* r = zi + (m0 - 1) * 32;
    u32 P = r[lp], C = r[l], N = r[ln];
    float zP = bf2f((u16)(P >> 16));
    float z0 = bf2f((u16)C), z1 = bf2f((u16)(C >> 16));
    float z2 = bf2f((u16)N);
    gp0 = fmaf(3.f, z0, tA0 * zP);
    gp1 = fmaf(3.f, z0, z1);
    gp2 = fmaf(3.f, z1, z0);
    gp3 = fmaf(3.f, z1, z2);
  }
  const u32* r = zi + m0 * 32;
  u32 P = r[lp], C = r[l], N = r[ln];

#pragma unroll
  for (int i = 0; i < 4; ++i) {
    int m = m0 + i;
    float zP = bf2f((u16)(P >> 16));
    float z0 = bf2f((u16)C), z1 = bf2f((u16)(C >> 16));
    float z2 = bf2f((u16)N);
    if (i < 3) { r += 32; P = r[lp]; C = r[l]; N = r[ln]; }
    float g0 = fmaf(3.f, z0, tA0 * zP);   // col 4l
    float g1 = fmaf(3.f, z0, z1);         // col 4l+1
    float g2 = fmaf(3.f, z1, z0);         // col 4l+2
    float g3 = fmaf(3.f, z1, z2);         // col 4l+3 (l=31: dropped)
    float* pe = ob + (size_t)(2 * m) * WO + 4 * l;
    if (m > 0) {  // row 2m-1 = 3*gp + g
      float* po = pe - WO;
      float v0 = fmaf(fmaf(3.f, gp0, g0), 0.0625f, bv);
      float v1 = fmaf(fmaf(3.f, gp1, g1), 0.0625f, bv);
      float v2 = fmaf(fmaf(3.f, gp2, g2), 0.0625f, bv);
      float v3 = fmaf(fmaf(3.f, gp3, g3), 0.0625f, bv);
      if (full) { float vv[4] = {v0, v1, v2, v3}; __builtin_memcpy(po, vv, 16); }
      else { po[0] = v0; po[1] = v1; po[2] = v2; }
    }
    {  // row 2m = gp + 3*g
      float v0 = fmaf(fmaf(3.f, g0, gp0), 0.0625f, bv);
      float v1 = fmaf(fmaf(3.f, g1, gp1), 0.0625f, bv);
      float v2 = fmaf(fmaf(3.f, g2, gp2), 0.0625f, bv);
      float v3 = fmaf(fmaf(3.f, g3, gp3), 0.0625f, bv);
      if (full) { float vv[4] = {v0, v1, v2, v3}; __builtin_memcpy(pe, vv, 16); }
      else { pe[0] = v0; pe[1] = v1; pe[2] = v2; }
    }
    gp0 = g0; gp1 = g1; gp2 = g2; gp3 = g3;
  }
}

// Fallback (no workspace).
__global__ __launch_bounds__(256) void fallback_kernel(
    const float* __restrict__ x, const float* __restrict__ w,
    const float* __restrict__ bias, float* __restrict__ out) {
  u32 idx = blockIdx.x * 256u + threadIdx.x;
  const u32 total = (u32)B_ * COUT * HO * WO;
  if (idx >= total) return;
  u32 j = idx % WO;
  u32 r1 = idx / WO;
  u32 i = r1 % HO;
  u32 bo = r1 / HO;
  int o = (int)(bo & 511u);
  int b = (int)(bo >> 9);
  int m = (int)(i >> 1), n = (int)(j >> 1);
  int ie = !(i & 1), je = !(j & 1);
  int rA = ie ? m - 1 : m;
  int cA = je ? n - 1 : n;
  float w_r0 = ie ? 1.f : 3.f, w_r1 = ie ? 3.f : 1.f;
  float w_c0 = je ? 1.f : 3.f, w_c1 = je ? 3.f : 1.f;
  const float* xb = x + (size_t)b * CIN * S_;
  float acc = 0.f;
  for (int cc = 0; cc < CIN; ++cc) {
    const float* xc = xb + (size_t)cc * S_;
    float y = 0.f;
    if (rA >= 0) {
      if (cA >= 0) y += w_r0 * w_c0 * xc[rA * 64 + cA];
      y += w_r0 * w_c1 * xc[rA * 64 + cA + 1];
    }
    if (cA >= 0) y += w_r1 * w_c0 * xc[(rA + 1) * 64 + cA];
    y += w_r1 * w_c1 * xc[(rA + 1) * 64 + cA + 1];
    acc += y * w[(size_t)o * CIN + cc];
  }
  out[idx] = acc * 0.0625f + bias[o];
}

extern "C" void kernel_launch(void* const* d_in, const int* in_sizes, int n_in,
                              void* d_out, int out_size, void* d_ws,
                              size_t ws_size, hipStream_t stream) {
  const float* x = (const float*)d_in[0];
  const float* w = (const float*)d_in[2];
  const float* bias = (const float*)d_in[3];
  float* out = (float*)d_out;

  const size_t xt_bytes = (size_t)B_ * S_ * CIN * 2;       // 64 MiB
  const size_t wt_off = xt_bytes;
  const size_t wt_bytes = (size_t)COUT * CIN * 2;          // 512 KiB
  const size_t z_off = wt_off + ((wt_bytes + 255) & ~(size_t)255);
  const size_t need = z_off + (size_t)B_ * COUT * S_ * 2;  // ~128.5 MiB
  const size_t total_out = (size_t)B_ * COUT * HO * WO;
  const u32 nblk_out = (u32)((total_out + 255) / 256);

  if (ws_size >= need) {
    u16* xt = (u16*)d_ws;
    u16* wt = (u16*)((char*)d_ws + wt_off);
    u16* zz = (u16*)((char*)d_ws + z_off);
    conv_w_kernel<<<128, 256, 0, stream>>>(w, wt);
    conv_x_kernel<<<dim3(32, 16, B_), 256, 0, stream>>>(x, xt);
    gemm_kernel<<<dim3(32, 4, B_), 256, 0, stream>>>(wt, xt, zz);
    // 8 waves/image, 4 waves/block -> B_*COUT*8/4 = 16384 blocks
    upsample_kernel<<<(B_ * COUT * 8) / 4, 256, 0, stream>>>(zz, bias, out);
  } else {
    fallback_kernel<<<nblk_out, 256, 0, stream>>>(x, w, bias, out);
  }
}